// Round 2
// baseline (39297.641 us; speedup 1.0000x reference)
//
#include <hip/hip_runtime.h>
#include <hip/hip_bf16.h>

#define B_SZ 1024
#define T_ENC 384
#define T_DEC 128
#define I_SZ 128
#define H_SZ 512

typedef __attribute__((ext_vector_type(8))) short short8;
typedef __attribute__((ext_vector_type(4))) float floatx4;
typedef unsigned short ushort_t;

__device__ __forceinline__ ushort_t f2bf(float x) {
    union { float f; unsigned int i; } v; v.f = x;
    unsigned int u = v.i;
    unsigned int r = (u + 0x7fffu + ((u >> 16) & 1u)) >> 16;
    return (ushort_t)r;
}
__device__ __forceinline__ float sigm(float x) { return 1.0f / (1.0f + __expf(-x)); }

// Software grid barrier (all blocks resident by construction).
// bar[0] = arrival count, bar[1] = generation. Device-scope atomics +
// __threadfence (agent-scope fence: cross-XCD L2 writeback/inv on gfx950).
__device__ __forceinline__ void gbar(unsigned* bar, unsigned nb) {
    __syncthreads();
    if (threadIdx.x == 0) {
        __threadfence();   // release: publish this block's writes device-wide
        unsigned g = __hip_atomic_load(&bar[1], __ATOMIC_RELAXED, __HIP_MEMORY_SCOPE_AGENT);
        unsigned arrived = __hip_atomic_fetch_add(&bar[0], 1u, __ATOMIC_RELAXED, __HIP_MEMORY_SCOPE_AGENT);
        if (arrived == nb - 1) {
            __hip_atomic_store(&bar[0], 0u, __ATOMIC_RELAXED, __HIP_MEMORY_SCOPE_AGENT);
            __threadfence();
            __hip_atomic_store(&bar[1], g + 1u, __ATOMIC_RELAXED, __HIP_MEMORY_SCOPE_AGENT);
        } else {
            while (__hip_atomic_load(&bar[1], __ATOMIC_RELAXED, __HIP_MEMORY_SCOPE_AGENT) == g)
                __builtin_amdgcn_s_sleep(2);
        }
        __threadfence();   // acquire: see other blocks' writes
    }
    __syncthreads();
}

// fp32 -> bf16 bulk convert (weights, once per launch). n % 1024 == 0.
__global__ __launch_bounds__(256) void cvt_f32_bf16(
    const float* __restrict__ src, ushort_t* __restrict__ dst, int n)
{
    int i = (blockIdx.x * 256 + threadIdx.x) * 4;
    if (i < n) {
        float4 v = *(const float4*)(src + i);
        short4 s = { (short)f2bf(v.x), (short)f2bf(v.y), (short)f2bf(v.z), (short)f2bf(v.w) };
        *(short4*)(dst + i) = s;
    }
}

// dec_in(t=0) = bf16(x[:, -1, :])
__global__ void copy_last(const float* __restrict__ x, ushort_t* __restrict__ dst)
{
    int i = blockIdx.x * 256 + threadIdx.x;           // 0 .. 131071
    int b = i >> 7, k = i & 127;
    dst[i] = f2bf(x[((size_t)b * T_ENC + (T_ENC - 1)) * I_SZ + k]);
}

#define BM 64
#define BN 32
#define KC 64
#define LDSW (KC + 8)    // 72 shorts: 144B row stride, 16B-aligned, breaks bank stride
#define DLW  (I_SZ + 8)  // 136 shorts: DecIn stride

// XCD-aware swizzle: bid%8 = XCD (dispatch round-robin heuristic). Pin 2 col-groups
// per XCD so each XCD's weight slice stays L2-resident across the persistent run.
__device__ __forceinline__ void tile_of(int bid, int& row0, int& col0) {
    int xcd = bid & 7, q = bid >> 3;          // q in [0,32)
    int cgp = xcd * 2 + (q & 1);              // col-group 0..15
    int rg = q >> 1;                          // row-group 0..15
    row0 = rg * BM; col0 = cgp * BN;
}

__device__ __forceinline__ void load_bias(
    const float* bih, const float* bhh, int col0, int l15, float (&bs)[4][2])
{
#pragma unroll
    for (int g = 0; g < 4; ++g)
#pragma unroll
        for (int n = 0; n < 2; ++n) {
            int gcol = col0 + n * 16 + l15;
            bs[g][n] = bih[g * H_SZ + gcol] + bhh[g * H_SZ + gcol];
        }
}

// One LSTM cell step for a 64row x (4 gates x 32)col tile; c and biases in registers.
// AMODE: 0 = A1 bf16 global, 1 = A1 fp32 global (encoder x), 2 = A1 in LDS (DecIn, stride DLW)
template<int AMODE>
__device__ __forceinline__ void cell_step(
    int row0, int col0,
    const void* A1v, int lda1, int K1,
    const ushort_t* W1, const ushort_t* A2, const ushort_t* W2,
    const float (&bs)[4][2], float (&creg)[2][4],
    ushort_t* h_out, short* As, short* Ws)
{
    const int tid  = threadIdx.x;
    const int wave = tid >> 6;
    const int lane = tid & 63;
    const int quad = lane >> 4;
    const int l15  = lane & 15;

    floatx4 acc[4][2];
#pragma unroll
    for (int g = 0; g < 4; ++g)
#pragma unroll
        for (int n = 0; n < 2; ++n)
            acc[g][n] = (floatx4){0.f, 0.f, 0.f, 0.f};

    const int KT = K1 + H_SZ;
    for (int kb = 0; kb < KT; kb += KC) {
        const ushort_t* wsrc; int wld;
        if (kb < K1) { wsrc = W1 + kb;        wld = K1;  }
        else         { wsrc = W2 + (kb - K1); wld = H_SZ; }

        if (AMODE == 1 && kb < K1) {
            const float* af = (const float*)A1v + kb;
#pragma unroll
            for (int it = 0; it < 4; ++it) {
                int idx = tid + it * 256;          // 0..1023
                int r = idx >> 4, cc2 = idx & 15;
                float4 v = *(const float4*)(af + (size_t)(row0 + r) * lda1 + cc2 * 4);
                short4 s = { (short)f2bf(v.x), (short)f2bf(v.y), (short)f2bf(v.z), (short)f2bf(v.w) };
                *(short4*)(void*)&As[r * LDSW + cc2 * 4] = s;
            }
        } else if (!(AMODE == 2 && kb < K1)) {
            const ushort_t* ab; int ald;
            if (kb < K1) { ab = (const ushort_t*)A1v + kb; ald = lda1; }
            else         { ab = A2 + (kb - K1);            ald = H_SZ; }
#pragma unroll
            for (int it = 0; it < 2; ++it) {
                int idx = tid + it * 256;          // 0..511
                int r = idx >> 3, cch = idx & 7;
                int4 v = *(const int4*)(const void*)(ab + (size_t)(row0 + r) * ald + cch * 8);
                *(int4*)(void*)&As[r * LDSW + cch * 8] = v;
            }
        }
        // stage W: 4 gates x 32 rows x 8 chunks (16B)
#pragma unroll
        for (int it = 0; it < 4; ++it) {
            int idx = tid + it * 256;              // 0..1023
            int rr = idx >> 3, cch = idx & 7;      // rr = g*32 + r
            int g = rr >> 5, r = rr & 31;
            int4 v = *(const int4*)(const void*)(wsrc + (size_t)(g * H_SZ + col0 + r) * wld + cch * 8);
            *(int4*)(void*)&Ws[rr * LDSW + cch * 8] = v;
        }
        __syncthreads();

#pragma unroll
        for (int ks = 0; ks < 2; ++ks) {
            const int ko = ks * 32 + quad * 8;
            short8 a;
            if (AMODE == 2 && kb < K1)
                a = *(const short8*)(const void*)&((const short*)A1v)[(wave * 16 + l15) * DLW + kb + ko];
            else
                a = *(const short8*)(const void*)&As[(wave * 16 + l15) * LDSW + ko];
#pragma unroll
            for (int g = 0; g < 4; ++g)
#pragma unroll
                for (int n = 0; n < 2; ++n) {
                    short8 b = *(const short8*)(const void*)&Ws[(g * BN + n * 16 + l15) * LDSW + ko];
                    acc[g][n] = __builtin_amdgcn_mfma_f32_16x16x32_bf16(a, b, acc[g][n], 0, 0, 0);
                }
        }
        __syncthreads();
    }

#pragma unroll
    for (int n = 0; n < 2; ++n) {
        const int gcol = col0 + n * 16 + l15;
#pragma unroll
        for (int r = 0; r < 4; ++r) {
            const int grow = row0 + wave * 16 + quad * 4 + r;
            const float zi = acc[0][n][r] + bs[0][n];
            const float zf = acc[1][n][r] + bs[1][n];
            const float zg = acc[2][n][r] + bs[2][n];
            const float zo = acc[3][n][r] + bs[3][n];
            const float cn = sigm(zf) * creg[n][r] + sigm(zi) * tanhf(zg);
            creg[n][r] = cn;
            h_out[(size_t)grow * H_SZ + gcol] = f2bf(sigm(zo) * tanhf(cn));
        }
    }
}

// Persistent encoder: 512 blocks (2/CU, all resident).
// Blocks 0..255: L0(t) for t=0..383.  Blocks 256..511: L1(t-1) for t=1..384.
// One software grid barrier per step replaces one kernel launch. c0/c1 stay in
// registers for all 384 steps and are written out once at the end.
__global__ __launch_bounds__(256, 2) void enc_persist(
    const float* x,
    const ushort_t* Wih0, const ushort_t* Whh0, const float* bih0, const float* bhh0,
    const ushort_t* Wih1, const ushort_t* Whh1, const float* bih1, const float* bhh1,
    ushort_t* h0a, ushort_t* h0b, ushort_t* h1a, ushort_t* h1b,
    float* c0, float* c1, unsigned* bar)
{
    __shared__ short As[BM * LDSW];
    __shared__ short Ws[4 * BN * LDSW];

    const int tid = threadIdx.x;
    const int bid = blockIdx.x;
    const bool isL0 = (bid < 256);
    int row0, col0; tile_of(isL0 ? bid : (bid - 256), row0, col0);
    const int lane = tid & 63, l15 = lane & 15, quad = lane >> 4, wave = tid >> 6;

    float bs[4][2];
    load_bias(isL0 ? bih0 : bih1, isL0 ? bhh0 : bhh1, col0, l15, bs);
    float creg[2][4];
#pragma unroll
    for (int n = 0; n < 2; ++n)
#pragma unroll
        for (int r = 0; r < 4; ++r) creg[n][r] = 0.f;

    ushort_t *h0c = h0a, *h0n = h0b, *h1c = h1a, *h1n = h1b;

    for (int t = 0; t <= T_ENC; ++t) {
        if (isL0) {
            if (t < T_ENC)
                cell_step<1>(row0, col0, x + (size_t)t * I_SZ, T_ENC * I_SZ, I_SZ,
                             Wih0, h0c, Whh0, bs, creg, h0n, As, Ws);
        } else {
            if (t > 0)
                cell_step<0>(row0, col0, h0c, H_SZ, H_SZ,
                             Wih1, h1c, Whh1, bs, creg, h1n, As, Ws);
        }
        gbar(bar, 512);
        if (t < T_ENC) { ushort_t* tmp = h0c; h0c = h0n; h0n = tmp; }
        if (t > 0)     { ushort_t* tmp = h1c; h1c = h1n; h1n = tmp; }
    }
    // final c states for the decoder (full coverage: 16 rg x 16 cg tiles)
    float* cdst = isL0 ? c0 : c1;
#pragma unroll
    for (int n = 0; n < 2; ++n)
#pragma unroll
        for (int r = 0; r < 4; ++r) {
            int grow = row0 + wave * 16 + quad * 4 + r;
            int gcol = col0 + n * 16 + l15;
            cdst[(size_t)grow * H_SZ + gcol] = creg[n][r];
        }
}

// Persistent decoder: 256 blocks (all resident). Each block owns the same (rg,cg)
// tile of BOTH layers; c0/c1 tiles live in registers the whole run.
// Per step t: [fc(t-1)+out + L0(t)]  barrier  [L1(t)]  barrier.
// Final iteration t==T_DEC runs fc(T_DEC-1) only (replaces fc_last).
__global__ __launch_bounds__(256, 2) void dec_persist(
    const ushort_t* dec0, const ushort_t* fcw, const float* fcb, float* out,
    const ushort_t* Wih0, const ushort_t* Whh0, const float* bih0, const float* bhh0,
    const ushort_t* Wih1, const ushort_t* Whh1, const float* bih1, const float* bhh1,
    ushort_t* h0a, ushort_t* h0b, ushort_t* h1a, ushort_t* h1b,
    const float* c0in, const float* c1in, unsigned* bar)
{
    __shared__ short As[BM * LDSW];
    __shared__ short Ws[4 * BN * LDSW];
    __shared__ short DecIn[BM * DLW];

    const int tid = threadIdx.x;
    const int wave = tid >> 6, lane = tid & 63, quad = lane >> 4, l15 = lane & 15;
    int row0, col0; tile_of(blockIdx.x, row0, col0);
    const int cgrp = col0 / BN;

    float bs0[4][2], bs1[4][2];
    load_bias(bih0, bhh0, col0, l15, bs0);
    load_bias(bih1, bhh1, col0, l15, bs1);

    float c0reg[2][4], c1reg[2][4];
#pragma unroll
    for (int n = 0; n < 2; ++n)
#pragma unroll
        for (int r = 0; r < 4; ++r) {
            int grow = row0 + wave * 16 + quad * 4 + r;
            int gcol = col0 + n * 16 + l15;
            c0reg[n][r] = c0in[(size_t)grow * H_SZ + gcol];
            c1reg[n][r] = c1in[(size_t)grow * H_SZ + gcol];
        }

    ushort_t *h0c = h0a, *h0n = h0b, *h1c = h1a, *h1n = h1b;

    for (int t = 0; t <= T_DEC; ++t) {
        // ---------- phase A: fc(t-1) -> DecIn (+ out(t-1)), then L0(t) ----------
        if (t > 0) {
            float* outp = out + (size_t)(t - 1) * I_SZ;
            floatx4 a2[8];
#pragma unroll
            for (int n = 0; n < 8; ++n) a2[n] = (floatx4){0.f, 0.f, 0.f, 0.f};
            for (int kb = 0; kb < H_SZ; kb += KC) {
#pragma unroll
                for (int it = 0; it < 2; ++it) {
                    int idx = tid + it * 256;
                    int r = idx >> 3, cch = idx & 7;
                    int4 v = *(const int4*)(const void*)(h1c + (size_t)(row0 + r) * H_SZ + kb + cch * 8);
                    *(int4*)(void*)&As[r * LDSW + cch * 8] = v;
                }
#pragma unroll
                for (int it = 0; it < 4; ++it) {
                    int idx = tid + it * 256;          // 0..1023
                    int r = idx >> 3, cch = idx & 7;   // r 0..127
                    int4 v = *(const int4*)(const void*)(fcw + (size_t)r * H_SZ + kb + cch * 8);
                    *(int4*)(void*)&Ws[r * LDSW + cch * 8] = v;
                }
                __syncthreads();
#pragma unroll
                for (int ks = 0; ks < 2; ++ks) {
                    const int ko = ks * 32 + quad * 8;
                    short8 a = *(const short8*)(const void*)&As[(wave * 16 + l15) * LDSW + ko];
#pragma unroll
                    for (int n = 0; n < 8; ++n) {
                        short8 b = *(const short8*)(const void*)&Ws[(n * 16 + l15) * LDSW + ko];
                        a2[n] = __builtin_amdgcn_mfma_f32_16x16x32_bf16(a, b, a2[n], 0, 0, 0);
                    }
                }
                __syncthreads();
            }
#pragma unroll
            for (int n = 0; n < 8; ++n) {
                const int col = n * 16 + l15;
                const float bias = fcb[col];
#pragma unroll
                for (int r = 0; r < 4; ++r) {
                    const int lrow = wave * 16 + quad * 4 + r;
                    const float v = a2[n][r] + bias;
                    DecIn[lrow * DLW + col] = (short)f2bf(v);
                    if (cgrp == 0)
                        outp[(size_t)(row0 + lrow) * T_DEC * I_SZ + col] = v;
                }
            }
        } else {
            // t==0: dec_in from global bf16 buffer
#pragma unroll
            for (int it = 0; it < 4; ++it) {
                int idx = tid + it * 256;              // 0..1023
                int r = idx >> 4, cch = idx & 15;
                int4 v = *(const int4*)(const void*)(dec0 + (size_t)(row0 + r) * I_SZ + cch * 8);
                *(int4*)(void*)&DecIn[r * DLW + cch * 8] = v;
            }
        }
        __syncthreads();

        if (t < T_DEC)
            cell_step<2>(row0, col0, (const void*)DecIn, DLW, I_SZ,
                         Wih0, h0c, Whh0, bs0, c0reg, h0n, As, Ws);
        gbar(bar, 256);

        // ---------- phase B: L1(t) ----------
        if (t < T_DEC) {
            cell_step<0>(row0, col0, h0n, H_SZ, H_SZ,
                         Wih1, h1c, Whh1, bs1, c1reg, h1n, As, Ws);
            gbar(bar, 256);
            { ushort_t* tmp = h0c; h0c = h0n; h0n = tmp; }
            { ushort_t* tmp = h1c; h1c = h1n; h1n = tmp; }
        }
    }
}

extern "C" void kernel_launch(void* const* d_in, const int* in_sizes, int n_in,
                              void* d_out, int out_size, void* d_ws, size_t ws_size,
                              hipStream_t stream)
{
    (void)in_sizes; (void)n_in; (void)out_size; (void)ws_size;
    const float* x     = (const float*)d_in[0];
    const float* W_ih0 = (const float*)d_in[1];
    const float* W_hh0 = (const float*)d_in[2];
    const float* b_ih0 = (const float*)d_in[3];
    const float* b_hh0 = (const float*)d_in[4];
    const float* W_ih1 = (const float*)d_in[5];
    const float* W_hh1 = (const float*)d_in[6];
    const float* b_ih1 = (const float*)d_in[7];
    const float* b_hh1 = (const float*)d_in[8];
    const float* fc_w  = (const float*)d_in[9];
    const float* fc_b  = (const float*)d_in[10];
    float* out = (float*)d_out;

    const int NW_IH0 = 4 * H_SZ * I_SZ;   // 262144
    const int NW_HH  = 4 * H_SZ * H_SZ;   // 1048576
    const int NW_FC  = I_SZ * H_SZ;       // 65536
    char* w = (char*)d_ws;
    ushort_t* wb_ih0 = (ushort_t*)w;  w += (size_t)NW_IH0 * 2;
    ushort_t* wb_hh0 = (ushort_t*)w;  w += (size_t)NW_HH  * 2;
    ushort_t* wb_ih1 = (ushort_t*)w;  w += (size_t)NW_HH  * 2;
    ushort_t* wb_hh1 = (ushort_t*)w;  w += (size_t)NW_HH  * 2;
    ushort_t* wb_fc  = (ushort_t*)w;  w += (size_t)NW_FC  * 2;
    const size_t HB2 = (size_t)B_SZ * H_SZ * 2;    // 1 MB bf16
    const size_t HB4 = (size_t)B_SZ * H_SZ * 4;    // 2 MB fp32
    ushort_t* h0a = (ushort_t*)w;  w += HB2;
    ushort_t* h0b = (ushort_t*)w;  w += HB2;
    ushort_t* h1a = (ushort_t*)w;  w += HB2;
    ushort_t* h1b = (ushort_t*)w;  w += HB2;
    float*    c0  = (float*)w;     w += HB4;
    float*    c1  = (float*)w;     w += HB4;
    ushort_t* dec0 = (ushort_t*)w; w += (size_t)B_SZ * I_SZ * 2;
    unsigned* bar = (unsigned*)w;  w += 16;        // [cnt, gen, pad, pad]

    cvt_f32_bf16<<<NW_IH0 / 1024, 256, 0, stream>>>(W_ih0, wb_ih0, NW_IH0);
    cvt_f32_bf16<<<NW_HH  / 1024, 256, 0, stream>>>(W_hh0, wb_hh0, NW_HH);
    cvt_f32_bf16<<<NW_HH  / 1024, 256, 0, stream>>>(W_ih1, wb_ih1, NW_HH);
    cvt_f32_bf16<<<NW_HH  / 1024, 256, 0, stream>>>(W_hh1, wb_hh1, NW_HH);
    cvt_f32_bf16<<<NW_FC  / 1024, 256, 0, stream>>>(fc_w,  wb_fc,  NW_FC);

    hipMemsetAsync(h0a, 0, HB2, stream);
    hipMemsetAsync(h1a, 0, HB2, stream);
    hipMemsetAsync(bar, 0, 16, stream);
    copy_last<<<512, 256, 0, stream>>>(x, dec0);

    // whole encoder: ONE launch, software grid barrier between steps
    enc_persist<<<512, 256, 0, stream>>>(
        x, wb_ih0, wb_hh0, b_ih0, b_hh0,
        wb_ih1, wb_hh1, b_ih1, b_hh1,
        h0a, h0b, h1a, h1b, c0, c1, bar);

    // whole decoder (incl. final fc): ONE launch
    dec_persist<<<256, 256, 0, stream>>>(
        dec0, wb_fc, fc_b, out,
        wb_ih0, wb_hh0, b_ih0, b_hh0,
        wb_ih1, wb_hh1, b_ih1, b_hh1,
        h0a, h0b, h1a, h1b, c0, c1, bar);
}

// Round 4
// 22232.324 us; speedup vs baseline: 1.7676x; 1.7676x over previous
//
#include <hip/hip_runtime.h>
#include <hip/hip_bf16.h>

#define B_SZ 1024
#define T_ENC 384
#define T_DEC 128
#define I_SZ 128
#define H_SZ 512

typedef __attribute__((ext_vector_type(8))) short short8;
typedef __attribute__((ext_vector_type(4))) float floatx4;
typedef unsigned short ushort_t;
typedef unsigned long long u64;

__device__ __forceinline__ ushort_t f2bf(float x) {
    union { float f; unsigned int i; } v; v.f = x;
    unsigned int u = v.i;
    unsigned int r = (u + 0x7fffu + ((u >> 16) & 1u)) >> 16;
    return (ushort_t)r;
}
__device__ __forceinline__ float sigm(float x) { return 1.0f / (1.0f + __expf(-x)); }

// ---- agent-coherent h access (bypasses non-coherent per-XCD L2, served by L3) ----
__device__ __forceinline__ void ald16(short* dst, const ushort_t* src) {
    u64 lo = __hip_atomic_load((const u64*)(const void*)src,       __ATOMIC_RELAXED, __HIP_MEMORY_SCOPE_AGENT);
    u64 hi = __hip_atomic_load((const u64*)(const void*)(src + 4), __ATOMIC_RELAXED, __HIP_MEMORY_SCOPE_AGENT);
    ((u64*)(void*)dst)[0] = lo;
    ((u64*)(void*)dst)[1] = hi;
}

// Bounded relaxed spin with fence fallback. Fast path: relaxed agent loads served
// from the coherence point — no L2 invalidation, weights stay L2-resident. If no
// progress for ~0.8 ms (4000x the expected barrier wait), issue __threadfence()
// (the round-2-proven visibility hammer) and keep spinning: hang-proof under any
// coherence model, full-speed if the relaxed model holds.
__device__ __forceinline__ void spin_ge(unsigned* p, unsigned tgt) {
    int n = 0;
    while (__hip_atomic_load(p, __ATOMIC_RELAXED, __HIP_MEMORY_SCOPE_AGENT) < tgt) {
        __builtin_amdgcn_s_sleep(4);          // ~256 cycles
        if (++n == (1 << 13)) { __threadfence(); n = 0; }
    }
}

// ---- fence-free monotone tree barrier --------------------------------------------
// Counters only increase -> no reset race, safe across graph replays only because
// the region is memset to 0 at the head of each capture. Line g (256B apart):
// [count, signal]; root line at ngrp. All relaxed AGENT atomics (RMWs execute at
// the coherence point). Publication of h: all waves drain vmcnt before arrival
// (agent stores ack at the coherence point), so a block observed as "arrived" has
// its h writes globally visible without any cache invalidation.
#define BLINE 64   // u32 per line (256B)
__device__ __forceinline__ void gbar(unsigned* bar, int bid, int nb, unsigned& step) {
    asm volatile("s_waitcnt vmcnt(0) lgkmcnt(0)" ::: "memory");   // all waves: publish h
    __syncthreads();
    if (threadIdx.x == 0) {
        const unsigned s1 = step + 1;
        const int grp = bid >> 3;
        const unsigned ngrp = (unsigned)(nb >> 3);
        unsigned* gcnt = bar + (size_t)grp * BLINE;
        unsigned* gsig = gcnt + 1;
        unsigned* rcnt = bar + (size_t)ngrp * BLINE;
        unsigned old = __hip_atomic_fetch_add(gcnt, 1u, __ATOMIC_RELAXED, __HIP_MEMORY_SCOPE_AGENT);
        if (old == 8u * s1 - 1u) {            // last arrival of this group
            unsigned rold = __hip_atomic_fetch_add(rcnt, 1u, __ATOMIC_RELAXED, __HIP_MEMORY_SCOPE_AGENT);
            if (rold != ngrp * s1 - 1u)
                spin_ge(rcnt, ngrp * s1);
            __hip_atomic_store(gsig, s1, __ATOMIC_RELAXED, __HIP_MEMORY_SCOPE_AGENT);
        } else {
            spin_ge(gsig, s1);
        }
    }
    step += 1;
    __syncthreads();
}

// fp32 -> bf16 bulk convert (weights, once per launch). n % 1024 == 0.
__global__ __launch_bounds__(256) void cvt_f32_bf16(
    const float* __restrict__ src, ushort_t* __restrict__ dst, int n)
{
    int i = (blockIdx.x * 256 + threadIdx.x) * 4;
    if (i < n) {
        float4 v = *(const float4*)(src + i);
        short4 s = { (short)f2bf(v.x), (short)f2bf(v.y), (short)f2bf(v.z), (short)f2bf(v.w) };
        *(short4*)(dst + i) = s;
    }
}

// dec_in(t=0) = bf16(x[:, -1, :])
__global__ void copy_last(const float* __restrict__ x, ushort_t* __restrict__ dst)
{
    int i = blockIdx.x * 256 + threadIdx.x;           // 0 .. 131071
    int b = i >> 7, k = i & 127;
    dst[i] = f2bf(x[((size_t)b * T_ENC + (T_ENC - 1)) * I_SZ + k]);
}

#define BM 64
#define BN 32
#define KC 64
#define LDSW (KC + 8)    // 72 shorts: 144B row stride, 16B-aligned, breaks bank stride
#define DLW  (I_SZ + 8)  // 136 shorts: DecIn stride

// XCD-aware swizzle: bid%8 = XCD (dispatch round-robin heuristic). Pin 2 col-groups
// per XCD so each XCD's weight slice stays L2-resident across the persistent run.
__device__ __forceinline__ void tile_of(int bid, int& row0, int& col0) {
    int xcd = bid & 7, q = bid >> 3;          // q in [0,32)
    int cgp = xcd * 2 + (q & 1);              // col-group 0..15
    int rg = q >> 1;                          // row-group 0..15
    row0 = rg * BM; col0 = cgp * BN;
}

__device__ __forceinline__ void load_bias(
    const float* bih, const float* bhh, int col0, int l15, float (&bs)[4][2])
{
#pragma unroll
    for (int g = 0; g < 4; ++g)
#pragma unroll
        for (int n = 0; n < 2; ++n) {
            int gcol = col0 + n * 16 + l15;
            bs[g][n] = bih[g * H_SZ + gcol] + bhh[g * H_SZ + gcol];
        }
}

// One LSTM cell step for a 64row x (4 gates x 32)col tile; c and biases in registers.
// AMODE: 0 = A1 bf16 global h-buffer (agent loads), 1 = A1 fp32 global (encoder x),
//        2 = A1 in LDS (DecIn, stride DLW).
// h-buffers use agent-coherent loads (bypass possibly-stale L2); weights W1/W2 use
// plain cached loads -> L2-resident for the whole run (no fences evict them).
// h_out written with packed 32-bit agent stores (write-through to the coherence point).
template<int AMODE>
__device__ __forceinline__ void cell_step(
    int row0, int col0,
    const void* A1v, int lda1, int K1,
    const ushort_t* W1, const ushort_t* A2, const ushort_t* W2,
    const float (&bs)[4][2], float (&creg)[2][4],
    ushort_t* h_out, short* As, short* Ws)
{
    const int tid  = threadIdx.x;
    const int wave = tid >> 6;
    const int lane = tid & 63;
    const int quad = lane >> 4;
    const int l15  = lane & 15;

    floatx4 acc[4][2];
#pragma unroll
    for (int g = 0; g < 4; ++g)
#pragma unroll
        for (int n = 0; n < 2; ++n)
            acc[g][n] = (floatx4){0.f, 0.f, 0.f, 0.f};

    const int KT = K1 + H_SZ;
    for (int kb = 0; kb < KT; kb += KC) {
        const ushort_t* wsrc; int wld;
        if (kb < K1) { wsrc = W1 + kb;        wld = K1;  }
        else         { wsrc = W2 + (kb - K1); wld = H_SZ; }

        if (AMODE == 1 && kb < K1) {
            const float* af = (const float*)A1v + kb;
#pragma unroll
            for (int it = 0; it < 4; ++it) {
                int idx = tid + it * 256;          // 0..1023
                int r = idx >> 4, cc2 = idx & 15;
                float4 v = *(const float4*)(af + (size_t)(row0 + r) * lda1 + cc2 * 4);
                short4 s = { (short)f2bf(v.x), (short)f2bf(v.y), (short)f2bf(v.z), (short)f2bf(v.w) };
                *(short4*)(void*)&As[r * LDSW + cc2 * 4] = s;
            }
        } else if (!(AMODE == 2 && kb < K1)) {
            const ushort_t* ab; int ald;
            if (kb < K1) { ab = (const ushort_t*)A1v + kb; ald = lda1; }
            else         { ab = A2 + (kb - K1);            ald = H_SZ; }
#pragma unroll
            for (int it = 0; it < 2; ++it) {
                int idx = tid + it * 256;          // 0..511
                int r = idx >> 3, cch = idx & 7;
                ald16(&As[r * LDSW + cch * 8], ab + (size_t)(row0 + r) * ald + cch * 8);
            }
        }
        // stage W: 4 gates x 32 rows x 8 chunks (16B) — plain cached (L2-resident)
#pragma unroll
        for (int it = 0; it < 4; ++it) {
            int idx = tid + it * 256;              // 0..1023
            int rr = idx >> 3, cch = idx & 7;      // rr = g*32 + r
            int g = rr >> 5, r = rr & 31;
            int4 v = *(const int4*)(const void*)(wsrc + (size_t)(g * H_SZ + col0 + r) * wld + cch * 8);
            *(int4*)(void*)&Ws[rr * LDSW + cch * 8] = v;
        }
        __syncthreads();

#pragma unroll
        for (int ks = 0; ks < 2; ++ks) {
            const int ko = ks * 32 + quad * 8;
            short8 a;
            if (AMODE == 2 && kb < K1)
                a = *(const short8*)(const void*)&((const short*)A1v)[(wave * 16 + l15) * DLW + kb + ko];
            else
                a = *(const short8*)(const void*)&As[(wave * 16 + l15) * LDSW + ko];
#pragma unroll
            for (int g = 0; g < 4; ++g)
#pragma unroll
                for (int n = 0; n < 2; ++n) {
                    short8 b = *(const short8*)(const void*)&Ws[(g * BN + n * 16 + l15) * LDSW + ko];
                    acc[g][n] = __builtin_amdgcn_mfma_f32_16x16x32_bf16(a, b, acc[g][n], 0, 0, 0);
                }
        }
        __syncthreads();
    }

#pragma unroll
    for (int n = 0; n < 2; ++n) {
        const int gcol = col0 + n * 16 + l15;
#pragma unroll
        for (int r = 0; r < 4; ++r) {
            const int grow = row0 + wave * 16 + quad * 4 + r;
            const float zi = acc[0][n][r] + bs[0][n];
            const float zf = acc[1][n][r] + bs[1][n];
            const float zg = acc[2][n][r] + bs[2][n];
            const float zo = acc[3][n][r] + bs[3][n];
            const float cn = sigm(zf) * creg[n][r] + sigm(zi) * tanhf(zg);
            creg[n][r] = cn;
            const float hv = sigm(zo) * tanhf(cn);
            const float hnb = __shfl_xor(hv, 1);
            if ((lane & 1) == 0) {   // lanes pair up: one 32-bit agent store per 2 cols
                unsigned p = (unsigned)f2bf(hv) | ((unsigned)f2bf(hnb) << 16);
                __hip_atomic_store((unsigned*)(void*)&h_out[(size_t)grow * H_SZ + gcol],
                                   p, __ATOMIC_RELAXED, __HIP_MEMORY_SCOPE_AGENT);
            }
        }
    }
}

// Persistent encoder: 512 blocks (2/CU, all resident — validated in round 2).
// Blocks 0..255: L0(t) for t=0..383.  Blocks 256..511: L1(t-1) for t=1..384.
__global__ __launch_bounds__(256, 2) void enc_persist(
    const float* x,
    const ushort_t* Wih0, const ushort_t* Whh0, const float* bih0, const float* bhh0,
    const ushort_t* Wih1, const ushort_t* Whh1, const float* bih1, const float* bhh1,
    ushort_t* h0a, ushort_t* h0b, ushort_t* h1a, ushort_t* h1b,
    float* c0, float* c1, unsigned* bar)
{
    __shared__ short As[BM * LDSW];
    __shared__ short Ws[4 * BN * LDSW];

    const int tid = threadIdx.x;
    const int bid = blockIdx.x;
    const bool isL0 = (bid < 256);
    int row0, col0; tile_of(isL0 ? bid : (bid - 256), row0, col0);
    const int lane = tid & 63, l15 = lane & 15, quad = lane >> 4, wave = tid >> 6;

    float bs[4][2];
    load_bias(isL0 ? bih0 : bih1, isL0 ? bhh0 : bhh1, col0, l15, bs);
    float creg[2][4];
#pragma unroll
    for (int n = 0; n < 2; ++n)
#pragma unroll
        for (int r = 0; r < 4; ++r) creg[n][r] = 0.f;

    ushort_t *h0c = h0a, *h0n = h0b, *h1c = h1a, *h1n = h1b;
    unsigned step = 0;

    for (int t = 0; t <= T_ENC; ++t) {
        if (isL0) {
            if (t < T_ENC)
                cell_step<1>(row0, col0, x + (size_t)t * I_SZ, T_ENC * I_SZ, I_SZ,
                             Wih0, h0c, Whh0, bs, creg, h0n, As, Ws);
        } else {
            if (t > 0)
                cell_step<0>(row0, col0, h0c, H_SZ, H_SZ,
                             Wih1, h1c, Whh1, bs, creg, h1n, As, Ws);
        }
        gbar(bar, bid, 512, step);
        if (t < T_ENC) { ushort_t* tmp = h0c; h0c = h0n; h0n = tmp; }
        if (t > 0)     { ushort_t* tmp = h1c; h1c = h1n; h1n = tmp; }
    }
    // final c states for the decoder (plain stores; kernel boundary publishes them)
    float* cdst = isL0 ? c0 : c1;
#pragma unroll
    for (int n = 0; n < 2; ++n)
#pragma unroll
        for (int r = 0; r < 4; ++r) {
            int grow = row0 + wave * 16 + quad * 4 + r;
            int gcol = col0 + n * 16 + l15;
            cdst[(size_t)grow * H_SZ + gcol] = creg[n][r];
        }
}

// Persistent decoder: 256 blocks (all resident). Each block owns the same (rg,cg)
// tile of BOTH layers; c0/c1 tiles live in registers the whole run.
// Per step t: [fc(t-1)+out + L0(t)]  barrier  [L1(t)]  barrier.
// Final iteration t==T_DEC runs fc(T_DEC-1) only (replaces fc_last).
__global__ __launch_bounds__(256, 2) void dec_persist(
    const ushort_t* dec0, const ushort_t* fcw, const float* fcb, float* out,
    const ushort_t* Wih0, const ushort_t* Whh0, const float* bih0, const float* bhh0,
    const ushort_t* Wih1, const ushort_t* Whh1, const float* bih1, const float* bhh1,
    ushort_t* h0a, ushort_t* h0b, ushort_t* h1a, ushort_t* h1b,
    const float* c0in, const float* c1in, unsigned* bar)
{
    __shared__ short As[BM * LDSW];
    __shared__ short Ws[4 * BN * LDSW];
    __shared__ short DecIn[BM * DLW];

    const int tid = threadIdx.x;
    const int wave = tid >> 6, lane = tid & 63, quad = lane >> 4, l15 = lane & 15;
    int row0, col0; tile_of(blockIdx.x, row0, col0);
    const int cgrp = col0 / BN;

    float bs0[4][2], bs1[4][2];
    load_bias(bih0, bhh0, col0, l15, bs0);
    load_bias(bih1, bhh1, col0, l15, bs1);

    float c0reg[2][4], c1reg[2][4];
#pragma unroll
    for (int n = 0; n < 2; ++n)
#pragma unroll
        for (int r = 0; r < 4; ++r) {
            int grow = row0 + wave * 16 + quad * 4 + r;
            int gcol = col0 + n * 16 + l15;
            c0reg[n][r] = c0in[(size_t)grow * H_SZ + gcol];
            c1reg[n][r] = c1in[(size_t)grow * H_SZ + gcol];
        }

    ushort_t *h0c = h0a, *h0n = h0b, *h1c = h1a, *h1n = h1b;
    unsigned step = 0;

    for (int t = 0; t <= T_DEC; ++t) {
        // ---------- phase A: fc(t-1) -> DecIn (+ out(t-1)), then L0(t) ----------
        if (t > 0) {
            float* outp = out + (size_t)(t - 1) * I_SZ;
            floatx4 a2[8];
#pragma unroll
            for (int n = 0; n < 8; ++n) a2[n] = (floatx4){0.f, 0.f, 0.f, 0.f};
            for (int kb = 0; kb < H_SZ; kb += KC) {
#pragma unroll
                for (int it = 0; it < 2; ++it) {
                    int idx = tid + it * 256;
                    int r = idx >> 3, cch = idx & 7;
                    ald16(&As[r * LDSW + cch * 8], h1c + (size_t)(row0 + r) * H_SZ + kb + cch * 8);
                }
#pragma unroll
                for (int it = 0; it < 4; ++it) {
                    int idx = tid + it * 256;          // 0..1023
                    int r = idx >> 3, cch = idx & 7;   // r 0..127
                    int4 v = *(const int4*)(const void*)(fcw + (size_t)r * H_SZ + kb + cch * 8);
                    *(int4*)(void*)&Ws[r * LDSW + cch * 8] = v;
                }
                __syncthreads();
#pragma unroll
                for (int ks = 0; ks < 2; ++ks) {
                    const int ko = ks * 32 + quad * 8;
                    short8 a = *(const short8*)(const void*)&As[(wave * 16 + l15) * LDSW + ko];
#pragma unroll
                    for (int n = 0; n < 8; ++n) {
                        short8 b = *(const short8*)(const void*)&Ws[(n * 16 + l15) * LDSW + ko];
                        a2[n] = __builtin_amdgcn_mfma_f32_16x16x32_bf16(a, b, a2[n], 0, 0, 0);
                    }
                }
                __syncthreads();
            }
#pragma unroll
            for (int n = 0; n < 8; ++n) {
                const int col = n * 16 + l15;
                const float bias = fcb[col];
#pragma unroll
                for (int r = 0; r < 4; ++r) {
                    const int lrow = wave * 16 + quad * 4 + r;
                    const float v = a2[n][r] + bias;
                    DecIn[lrow * DLW + col] = (short)f2bf(v);
                    if (cgrp == 0)
                        outp[(size_t)(row0 + lrow) * T_DEC * I_SZ + col] = v;
                }
            }
        } else {
            // t==0: dec_in from global bf16 buffer (written by an earlier dispatch)
#pragma unroll
            for (int it = 0; it < 4; ++it) {
                int idx = tid + it * 256;              // 0..1023
                int r = idx >> 4, cch = idx & 15;
                int4 v = *(const int4*)(const void*)(dec0 + (size_t)(row0 + r) * I_SZ + cch * 8);
                *(int4*)(void*)&DecIn[r * DLW + cch * 8] = v;
            }
        }
        __syncthreads();

        if (t < T_DEC)
            cell_step<2>(row0, col0, (const void*)DecIn, DLW, I_SZ,
                         Wih0, h0c, Whh0, bs0, c0reg, h0n, As, Ws);
        gbar(bar, blockIdx.x, 256, step);

        // ---------- phase B: L1(t) ----------
        if (t < T_DEC) {
            cell_step<0>(row0, col0, h0n, H_SZ, H_SZ,
                         Wih1, h1c, Whh1, bs1, c1reg, h1n, As, Ws);
            gbar(bar, blockIdx.x, 256, step);
            { ushort_t* tmp = h0c; h0c = h0n; h0n = tmp; }
            { ushort_t* tmp = h1c; h1c = h1n; h1n = tmp; }
        }
    }
}

extern "C" void kernel_launch(void* const* d_in, const int* in_sizes, int n_in,
                              void* d_out, int out_size, void* d_ws, size_t ws_size,
                              hipStream_t stream)
{
    (void)in_sizes; (void)n_in; (void)out_size; (void)ws_size;
    const float* x     = (const float*)d_in[0];
    const float* W_ih0 = (const float*)d_in[1];
    const float* W_hh0 = (const float*)d_in[2];
    const float* b_ih0 = (const float*)d_in[3];
    const float* b_hh0 = (const float*)d_in[4];
    const float* W_ih1 = (const float*)d_in[5];
    const float* W_hh1 = (const float*)d_in[6];
    const float* b_ih1 = (const float*)d_in[7];
    const float* b_hh1 = (const float*)d_in[8];
    const float* fc_w  = (const float*)d_in[9];
    const float* fc_b  = (const float*)d_in[10];
    float* out = (float*)d_out;

    const int NW_IH0 = 4 * H_SZ * I_SZ;   // 262144
    const int NW_HH  = 4 * H_SZ * H_SZ;   // 1048576
    const int NW_FC  = I_SZ * H_SZ;       // 65536
    char* w = (char*)d_ws;
    ushort_t* wb_ih0 = (ushort_t*)w;  w += (size_t)NW_IH0 * 2;
    ushort_t* wb_hh0 = (ushort_t*)w;  w += (size_t)NW_HH  * 2;
    ushort_t* wb_ih1 = (ushort_t*)w;  w += (size_t)NW_HH  * 2;
    ushort_t* wb_hh1 = (ushort_t*)w;  w += (size_t)NW_HH  * 2;
    ushort_t* wb_fc  = (ushort_t*)w;  w += (size_t)NW_FC  * 2;
    const size_t HB2 = (size_t)B_SZ * H_SZ * 2;    // 1 MB bf16
    const size_t HB4 = (size_t)B_SZ * H_SZ * 4;    // 2 MB fp32
    ushort_t* h0a = (ushort_t*)w;  w += HB2;
    ushort_t* h0b = (ushort_t*)w;  w += HB2;
    ushort_t* h1a = (ushort_t*)w;  w += HB2;
    ushort_t* h1b = (ushort_t*)w;  w += HB2;
    float*    c0  = (float*)w;     w += HB4;
    float*    c1  = (float*)w;     w += HB4;
    ushort_t* dec0 = (ushort_t*)w; w += (size_t)B_SZ * I_SZ * 2;
    // barrier regions: enc = 64 groups + root = 65 lines; dec = 32 groups + root = 33
    unsigned* bar_enc = (unsigned*)w;              // 65 * 256B
    unsigned* bar_dec = bar_enc + 65 * 64;         // 33 * 256B
    const size_t BAR_BYTES = (65 + 33) * 256;
    w += BAR_BYTES;

    cvt_f32_bf16<<<NW_IH0 / 1024, 256, 0, stream>>>(W_ih0, wb_ih0, NW_IH0);
    cvt_f32_bf16<<<NW_HH  / 1024, 256, 0, stream>>>(W_hh0, wb_hh0, NW_HH);
    cvt_f32_bf16<<<NW_HH  / 1024, 256, 0, stream>>>(W_ih1, wb_ih1, NW_HH);
    cvt_f32_bf16<<<NW_HH  / 1024, 256, 0, stream>>>(W_hh1, wb_hh1, NW_HH);
    cvt_f32_bf16<<<NW_FC  / 1024, 256, 0, stream>>>(fc_w,  wb_fc,  NW_FC);

    hipMemsetAsync(h0a, 0, HB2, stream);
    hipMemsetAsync(h1a, 0, HB2, stream);
    hipMemsetAsync(bar_enc, 0, BAR_BYTES, stream);
    copy_last<<<512, 256, 0, stream>>>(x, dec0);

    // whole encoder: ONE launch, fence-free tree barrier between steps
    enc_persist<<<512, 256, 0, stream>>>(
        x, wb_ih0, wb_hh0, b_ih0, b_hh0,
        wb_ih1, wb_hh1, b_ih1, b_hh1,
        h0a, h0b, h1a, h1b, c0, c1, bar_enc);

    // whole decoder (incl. final fc): ONE launch
    dec_persist<<<256, 256, 0, stream>>>(
        dec0, wb_fc, fc_b, out,
        wb_ih0, wb_hh0, b_ih0, b_hh0,
        wb_ih1, wb_hh1, b_ih1, b_hh1,
        h0a, h0b, h1a, h1b, c0, c1, bar_dec);
}